// Round 4
// baseline (237.353 us; speedup 1.0000x reference)
//
#include <hip/hip_runtime.h>
#include <hip/hip_bf16.h>
#include <stdint.h>

typedef unsigned short u16;
typedef __attribute__((ext_vector_type(8))) short short8;   // 8 x bf16 (4 VGPRs) MFMA A/B frag
typedef __attribute__((ext_vector_type(4))) float floatx4;  // MFMA C/D frag

#define DIM 1024

__device__ inline u16 f2bf(float f) {
  union { float f; uint32_t u; } v; v.f = f;
  uint32_t r = v.u + 0x7fffu + ((v.u >> 16) & 1u);  // RNE
  return (u16)(r >> 16);
}

// packed fp32x2 -> bf16x2 (v_cvt_pk_bf16_f32 on gfx950), RNE — bit-identical to f2bf
__device__ inline uint32_t f2bf2(float lo, float hi) {
  __hip_bfloat162 h = __float22bfloat162_rn(float2{lo, hi});
  union { __hip_bfloat162 h; uint32_t u; } v; v.h = h;
  return v.u;
}

// async global->LDS, 16B per lane; LDS dest is wave-uniform base (+lane*16 by HW)
__device__ inline void gload_lds16(const u16* g, u16* l) {
  __builtin_amdgcn_global_load_lds((const __attribute__((address_space(1))) uint32_t*)g,
                                   (__attribute__((address_space(3))) uint32_t*)l,
                                   16, 0, 0);
}

#define LGKM0 asm volatile("s_waitcnt lgkmcnt(0)" ::: "memory")
#define VMW(n) asm volatile("s_waitcnt vmcnt(" #n ")" ::: "memory")
#define BAR() do { asm volatile("" ::: "memory"); __builtin_amdgcn_s_barrier(); asm volatile("" ::: "memory"); } while (0)
#define PRIO1 __builtin_amdgcn_s_setprio(1)
#define PRIO0 __builtin_amdgcn_s_setprio(0)

// ---------------- fused prep: x->bf16, W->Wt bf16, bias gather, lsum zero ----------------
__global__ __launch_bounds__(256) void prep(const float* __restrict__ x,
                                            const float* __restrict__ Wq,
                                            const float* __restrict__ Wk,
                                            const float* __restrict__ Wv,
                                            const float* __restrict__ bq,
                                            const float* __restrict__ bk,
                                            const float* __restrict__ bv,
                                            u16* __restrict__ Xb,
                                            u16* __restrict__ Wt,
                                            float* __restrict__ bias,
                                            float* __restrict__ lsum) {
  __shared__ u16 tile[32][33];
  const int bx = blockIdx.x;
  if (bx < 8192) {
    size_t i = ((size_t)bx * 256 + threadIdx.x) * 4;
    float4 v = *(const float4*)(x + i);
    uint2 o;
    o.x = f2bf2(v.x, v.y);
    o.y = f2bf2(v.z, v.w);
    *(uint2*)(Xb + i) = o;
    if (bx < 8) {  // zero 8192 floats of lsum
      float4 z = {0.f, 0.f, 0.f, 0.f};
      *(float4*)(lsum + (size_t)bx * 1024 + threadIdx.x * 4) = z;
    }
    return;
  }
  const int t = bx - 8192;
  const int tz = t >> 10;            // 0..2  (weight index)
  const int bxx = t & 31;            // 32 col-tiles
  const int byy = (t >> 5) & 31;     // 32 row-tiles
  const float* W = (tz == 0) ? Wq : (tz == 1) ? Wk : Wv;
  u16* o = Wt + (size_t)tz * (1u << 20);
  if (bxx == 0 && byy == 0) {  // pack biases contiguously
    const float* bsrc = (tz == 0) ? bq : (tz == 1) ? bk : bv;
    float4 b4 = *(const float4*)(bsrc + threadIdx.x * 4);
    *(float4*)(bias + tz * 1024 + threadIdx.x * 4) = b4;
  }
  int c0 = bxx * 32, r0 = byy * 32;
  int tx = threadIdx.x & 31, ty = threadIdx.x >> 5;  // ty 0..7
#pragma unroll
  for (int p = 0; p < 4; ++p)
    tile[p * 8 + ty][tx] = f2bf(W[(size_t)(r0 + p * 8 + ty) * DIM + c0 + tx]);
  __syncthreads();
#pragma unroll
  for (int p = 0; p < 4; ++p)
    o[(size_t)(c0 + p * 8 + ty) * DIM + r0 + tx] = tile[tx][p * 8 + ty];
}

// ---------------- 4-phase-per-K-tile 256x256 GEMM core, K=1024 (NT=16) ----------------
// 8 waves 2Mx4N, per-wave 128x64 out, BK=64, 2 LDS K-tile buffers (tile U -> buf U&1).
// LDS buffer: A[256][64] + B[256][64] bf16 = 64 KiB; 2 bufs = 128 KiB.
// Swizzle: 16B-chunk slot s of row r holds global k-chunk s^(r&7); source pre-swizzled
// at staging (gload_lds dest linear), same XOR on ds_read -> conflict-free b128 (verified 0).
// Half-iter for tile U (4 phases, 16 MFMA each):
//   p1: RD B(p0)+B(p1)+A(q0) [12 rd];                MM(0,0)
//   p2:                       STG (U+2).B0;          MM(0,1)   [B-buf freed by p1]
//   p3: RD A(q1, reuse Aq);   STG (U+2).B1;          MM(1,0)
//   p4:                       STG (U+2).A0+A1;       MM(1,1); vmcnt(8); BAR
// Gate cover: tile U+2's stages (H.p2..p4) gated at end of H+1 -> 4-6 phases of
// latency cover (was 2 in round 3 -> ~400cy/phase stall).  Steady state: 16 loads
// outstanding at p4, vmcnt(8) drains exactly the previous half-iter's tile.
__device__ __forceinline__ void gemm1024_4ph(const u16* __restrict__ Ab,
                                             const u16* __restrict__ Bb,
                                             u16* __restrict__ lds,
                                             floatx4 (&acc)[8][4]) {
  constexpr int K = 1024;
  constexpr int NT = 16;
  constexpr int BUF = 32768;  // u16 per buffer
  const int tid = threadIdx.x;
  const int lane = tid & 63;
  const int w = tid >> 6;
  const int wm = (w >> 2) * 128;
  const int wn = (w & 3) * 64;
  const int fr = lane & 15;
  const int sl0 = (((lane >> 4)    ) ^ (fr & 7)) * 8;
  const int sl1 = (((lane >> 4) | 4) ^ (fr & 7)) * 8;
  const int rA = (wm + fr) * 64;           // + mi*1024 + slot
  const int rB = 16384 + (wn + fr) * 64;   // + ni*1024 + slot
  const int srow = tid >> 3;               // staging row 0..63 (+64 per sub-load)
  const int kc = ((tid & 7) ^ (srow & 7)) * 8;  // pre-swizzled source chunk
  const u16* ga = Ab + (size_t)srow * K + kc;
  const u16* gb = Bb + (size_t)srow * K + kc;
  u16* const ld0 = lds + w * 512;          // wave-uniform staging base

  short8 Aq[4][2], Bp[2][2][2];

#define STG_A(B_, TT, h) { u16* d_ = ld0 + (B_) * BUF + (h) * 8192;               \
    const u16* s_ = ga + (size_t)((h) * 128) * K + (TT) * 64;                     \
    gload_lds16(s_, d_); gload_lds16(s_ + (size_t)64 * K, d_ + 4096); }
#define STG_B(B_, TT, h) { u16* d_ = ld0 + (B_) * BUF + 16384 + (h) * 8192;       \
    const u16* s_ = gb + (size_t)((h) * 128) * K + (TT) * 64;                     \
    gload_lds16(s_, d_); gload_lds16(s_ + (size_t)64 * K, d_ + 4096); }
#define RD_A(B_, q) { const u16* p_ = lds + (B_) * BUF + rA + (q) * 4096;         \
    _Pragma("unroll") for (int m_ = 0; m_ < 4; ++m_) {                            \
      Aq[m_][0] = *(const short8*)(p_ + m_ * 1024 + sl0);                         \
      Aq[m_][1] = *(const short8*)(p_ + m_ * 1024 + sl1); } }
#define RD_B(B_, p) { const u16* q_ = lds + (B_) * BUF + rB + (p) * 2048;         \
    _Pragma("unroll") for (int n_ = 0; n_ < 2; ++n_) {                            \
      Bp[p][n_][0] = *(const short8*)(q_ + n_ * 1024 + sl0);                      \
      Bp[p][n_][1] = *(const short8*)(q_ + n_ * 1024 + sl1); } }
#define MM(q, p)                                                                  \
    _Pragma("unroll") for (int m_ = 0; m_ < 4; ++m_)                              \
    _Pragma("unroll") for (int n_ = 0; n_ < 2; ++n_)                              \
    _Pragma("unroll") for (int s_ = 0; s_ < 2; ++s_)                              \
      acc[(q) * 4 + m_][(p) * 2 + n_] = __builtin_amdgcn_mfma_f32_16x16x32_bf16(  \
          Aq[m_][s_], Bp[p][n_][s_], acc[(q) * 4 + m_][(p) * 2 + n_], 0, 0, 0);

#define HALF_ITER(U)                                                              \
  {                                                                               \
    const int u_ = (U) & 1;                                                       \
    const bool st_ = (U) + 2 < NT;                                                \
    /* p1 */                                                                      \
    RD_B(u_, 0); RD_B(u_, 1); RD_A(u_, 0);                                        \
    BAR(); LGKM0;                                                                 \
    PRIO1; MM(0, 0); PRIO0;                                                       \
    BAR();                                                                        \
    /* p2 */                                                                      \
    if (st_) STG_B(u_, (U) + 2, 0);                                               \
    BAR(); LGKM0;                                                                 \
    PRIO1; MM(0, 1); PRIO0;                                                       \
    BAR();                                                                        \
    /* p3 */                                                                      \
    RD_A(u_, 1);                                                                  \
    if (st_) STG_B(u_, (U) + 2, 1);                                               \
    BAR(); LGKM0;                                                                 \
    PRIO1; MM(1, 0); PRIO0;                                                       \
    BAR();                                                                        \
    /* p4 */                                                                      \
    if (st_) { STG_A(u_, (U) + 2, 0); STG_A(u_, (U) + 2, 1); }                    \
    BAR(); LGKM0;                                                                 \
    PRIO1; MM(1, 1); PRIO0;                                                       \
    if (st_) { VMW(8); } else { VMW(0); }                                         \
    BAR();                                                                        \
  }

  // prologue: stage tiles 0 and 1 fully; drain tile 0 (leave tile 1's 8 in flight)
  STG_A(0, 0, 0); STG_A(0, 0, 1); STG_B(0, 0, 0); STG_B(0, 0, 1);
  STG_A(1, 1, 0); STG_A(1, 1, 1); STG_B(1, 1, 0); STG_B(1, 1, 1);
  VMW(8);
  BAR();

  for (int j = 0; j < NT / 2; ++j) {
    HALF_ITER(2 * j);
    HALF_ITER(2 * j + 1);
  }
#undef STG_A
#undef STG_B
#undef RD_A
#undef RD_B
#undef MM
#undef HALF_ITER
}

// ---------------- Q|K projection: [8192 x 2048] = Xb x (Wq|Wk)^T, 256 blocks ----------------
__global__ __launch_bounds__(512, 2)
void qk_proj(const u16* __restrict__ Xb, const u16* __restrict__ Wt,
             u16* __restrict__ Q, const float* __restrict__ bias) {
  __shared__ __align__(16) u16 lds[65536];  // 128 KiB
  const int x = blockIdx.x;
  const int c = x & 7, j = x >> 3;
  const int mt = c * 4 + (j & 3);   // 0..31
  const int nt = j >> 2;            // 0..7 over combined N=2048 (Wq then Wk contiguous)
  const u16* Ab = Xb + (size_t)mt * 262144;
  const u16* Bb = Wt + (size_t)nt * 262144;
  floatx4 acc[8][4] = {};
  gemm1024_4ph(Ab, Bb, lds, acc);

  const int lane = threadIdx.x & 63;
  const int w = threadIdx.x >> 6;
  const int wm = (w >> 2) * 128, wn = (w & 3) * 64;
  const int er = (lane >> 4) * 4, ec = lane & 15;
  const int r0 = mt * 256 + wm;
  const int z = nt >> 2;                      // 0=Q, 1=K
  const int c0 = (nt & 3) * 256 + wn;
  u16* C = Q + (size_t)z * (8u << 20);
  const float* bz = bias + z * 1024;
  const float zs = (z == 0) ? 0.03125f : 1.0f;  // fold 1/sqrt(1024) into Q
#pragma unroll
  for (int mi = 0; mi < 8; ++mi)
#pragma unroll
    for (int ni = 0; ni < 4; ++ni) {
      const int col = c0 + ni * 16 + ec;
      const float bb = bz[col];
      const int row = r0 + mi * 16 + er;
      const uint32_t p0 = f2bf2((acc[mi][ni][0] + bb) * zs, (acc[mi][ni][1] + bb) * zs);
      const uint32_t p1 = f2bf2((acc[mi][ni][2] + bb) * zs, (acc[mi][ni][3] + bb) * zs);
      C[(size_t)(row + 0) * 1024 + col] = (u16)p0;
      C[(size_t)(row + 1) * 1024 + col] = (u16)(p0 >> 16);
      C[(size_t)(row + 2) * 1024 + col] = (u16)p1;
      C[(size_t)(row + 3) * 1024 + col] = (u16)(p1 >> 16);
    }
}

// ---------------- combined Vt projection (128 tiles) + score P~=exp(QK^T) (256 tiles) ----------------
__global__ __launch_bounds__(512, 2)
void vt_score(const u16* __restrict__ Xb, const u16* __restrict__ Wt,
              const u16* __restrict__ Q, u16* __restrict__ Vt,
              u16* __restrict__ P, float* __restrict__ lsum,
              const float* __restrict__ bias) {
  __shared__ __align__(16) u16 lds[65536];  // 128 KiB
  const int x = blockIdx.x;
  const u16 *Ab, *Bb;
  int mt, nt, z = 0;
  if (x < 128) {            // Vt: [1024 x 8192] = Wv^T x Xb^T
    mt = x & 3; nt = x >> 2;
    Ab = Wt + (size_t)2 * (1u << 20) + (size_t)mt * 262144;
    Bb = Xb + (size_t)nt * 262144;
  } else {                  // score z: [2048 x 2048] = Q[z] x K[z]^T
    const int xs = x - 128;
    z = xs >> 6;
    const int q = xs & 63;
    const int c = q & 7, jj = q >> 3;
    mt = (c & 3) * 2 + (jj & 1);
    nt = (c >> 2) * 4 + (jj >> 1);
    Ab = Q + (size_t)z * 2097152 + (size_t)mt * 262144;
    Bb = Q + 8388608 + (size_t)z * 2097152 + (size_t)nt * 262144;
  }
  floatx4 acc[8][4] = {};
  gemm1024_4ph(Ab, Bb, lds, acc);

  const int lane = threadIdx.x & 63;
  const int w = threadIdx.x >> 6;
  const int wm = (w >> 2) * 128, wn = (w & 3) * 64;
  const int er = (lane >> 4) * 4, ec = lane & 15;
  const int r0 = mt * 256 + wm;
  const int c0 = nt * 256 + wn;

  if (x < 128) {
    const float* bz = bias + 2 * 1024;  // bv, indexed by row (=h)
#pragma unroll
    for (int mi = 0; mi < 8; ++mi) {
      float bb[4];
#pragma unroll
      for (int r = 0; r < 4; ++r) bb[r] = bz[r0 + mi * 16 + er + r];
#pragma unroll
      for (int ni = 0; ni < 4; ++ni) {
        const int col = c0 + ni * 16 + ec;  // global s in [0,8192)
        const size_t base = (size_t)(col >> 11) * (1u << 21) + (col & 2047);
        const int row = r0 + mi * 16 + er;
        const uint32_t p0 = f2bf2(acc[mi][ni][0] + bb[0], acc[mi][ni][1] + bb[1]);
        const uint32_t p1 = f2bf2(acc[mi][ni][2] + bb[2], acc[mi][ni][3] + bb[3]);
        Vt[base + (size_t)(row + 0) * 2048] = (u16)p0;
        Vt[base + (size_t)(row + 1) * 2048] = (u16)(p0 >> 16);
        Vt[base + (size_t)(row + 2) * 2048] = (u16)p1;
        Vt[base + (size_t)(row + 3) * 2048] = (u16)(p1 >> 16);
      }
    }
  } else {
    u16* C = P + (size_t)z * (4u << 20);
    float* lz = lsum + z * 2048;
#pragma unroll
    for (int mi = 0; mi < 8; ++mi) {
      float rs[4] = {0.f, 0.f, 0.f, 0.f};
#pragma unroll
      for (int ni = 0; ni < 4; ++ni) {
        const int col = c0 + ni * 16 + ec;
        const int row = r0 + mi * 16 + er;
        float e[4];
#pragma unroll
        for (int r = 0; r < 4; ++r) {
          e[r] = exp2f(acc[mi][ni][r] * 1.44269504088896340736f);
          rs[r] += e[r];
        }
        const uint32_t p0 = f2bf2(e[0], e[1]);
        const uint32_t p1 = f2bf2(e[2], e[3]);
        C[(size_t)(row + 0) * 2048 + col] = (u16)p0;
        C[(size_t)(row + 1) * 2048 + col] = (u16)(p0 >> 16);
        C[(size_t)(row + 2) * 2048 + col] = (u16)p1;
        C[(size_t)(row + 3) * 2048 + col] = (u16)(p1 >> 16);
      }
#pragma unroll
      for (int o = 1; o < 16; o <<= 1)
#pragma unroll
        for (int r = 0; r < 4; ++r) rs[r] += __shfl_xor(rs[r], o);
      if ((lane & 15) == 0) {
#pragma unroll
        for (int r = 0; r < 4; ++r)
          atomicAdd(&lz[r0 + mi * 16 + er + r], rs[r]);
      }
    }
  }
}

// ---------------- out = (P~ Vt^T)/lsum: 128x256 tiles, K=2048, 2-phase half-iters, 256 blocks ----------------
__global__ __launch_bounds__(512, 2)
void pv_out(const u16* __restrict__ P, const u16* __restrict__ Vt,
            float* __restrict__ out, const float* __restrict__ lsum) {
  __shared__ __align__(16) u16 lds[49152];  // 96 KiB: 2 x (A 128x64 + B 256x64)
  constexpr int K = 2048;
  constexpr int NT = 32;
  constexpr int BUF = 24576;
  const int x = blockIdx.x;
  const int z = x >> 6, q = x & 63;
  const int c = q & 7, jj = q >> 3;
  const int mt = (c >> 1) * 4 + (jj & 3);   // 0..15
  const int nt = (c & 1) * 2 + (jj >> 2);   // 0..3
  const u16* Ab = P + (size_t)z * (4u << 20) + (size_t)mt * 128 * 2048;
  const u16* Bb = Vt + (size_t)z * (2u << 20) + (size_t)nt * 256 * 2048;

  const int tid = threadIdx.x;
  const int lane = tid & 63;
  const int w = tid >> 6;
  const int wm = (w >> 2) * 64;
  const int wn = (w & 3) * 64;
  const int fr = lane & 15;
  const int sl0 = (((lane >> 4)    ) ^ (fr & 7)) * 8;
  const int sl1 = (((lane >> 4) | 4) ^ (fr & 7)) * 8;
  const int rA = (wm + fr) * 64;
  const int rB = 8192 + (wn + fr) * 64;
  const int srow = tid >> 3;
  const int kc = ((tid & 7) ^ (srow & 7)) * 8;
  const u16* ga = Ab + (size_t)srow * K + kc;
  const u16* gb = Bb + (size_t)srow * K + kc;
  u16* const ld0 = lds + w * 512;

  short8 Aq[4][2], Bp[2][2][2];
  floatx4 acc[4][4] = {};

#define PSTG_A(B_, TT) { u16* d_ = ld0 + (B_) * BUF;                              \
    const u16* s_ = ga + (size_t)(TT) * 64;                                       \
    gload_lds16(s_, d_); gload_lds16(s_ + (size_t)64 * K, d_ + 4096); }
#define PSTG_B(B_, TT, h) { u16* d_ = ld0 + (B_) * BUF + 8192 + (h) * 8192;       \
    const u16* s_ = gb + (size_t)((h) * 128) * K + (TT) * 64;                     \
    gload_lds16(s_, d_); gload_lds16(s_ + (size_t)64 * K, d_ + 4096); }
#define PRD_A(B_) { const u16* p_ = lds + (B_) * BUF + rA;                        \
    _Pragma("unroll") for (int m_ = 0; m_ < 4; ++m_) {                            \
      Aq[m_][0] = *(const short8*)(p_ + m_ * 1024 + sl0);                         \
      Aq[m_][1] = *(const short8*)(p_ + m_ * 1024 + sl1); } }
#define PRD_B(B_, p) { const u16* q_ = lds + (B_) * BUF + rB + (p) * 2048;        \
    _Pragma("unroll") for (int n_ = 0; n_ < 2; ++n_) {                            \
      Bp[p][n_][0] = *(const short8*)(q_ + n_ * 1024 + sl0);                      \
      Bp[p][n_][1] = *(const short8*)(q_ + n_ * 1024 + sl1); } }
#define PMM(p)                                                                    \
    _Pragma("unroll") for (int m_ = 0; m_ < 4; ++m_)                              \
    _Pragma("unroll") for (int n_ = 0; n_ < 2; ++n_)                              \
    _Pragma("unroll") for (int s_ = 0; s_ < 2; ++s_)                              \
      acc[m_][(p) * 2 + n_] = __builtin_amdgcn_mfma_f32_16x16x32_bf16(            \
          Aq[m_][s_], Bp[p][n_][s_], acc[m_][(p) * 2 + n_], 0, 0, 0);

// 2-phase half-iter for tile U: p1 reads everything (16 rd) + PMM(0);
// p2 stages tile U+2 fully (6 loads, both A and B freed by p1) + PMM(1) + gate vmcnt(6).
#define PHALF(U)                                                                  \
  {                                                                               \
    const int u_ = (U) & 1;                                                       \
    const bool st_ = (U) + 2 < NT;                                                \
    /* p1 */                                                                      \
    PRD_B(u_, 0); PRD_B(u_, 1); PRD_A(u_);                                        \
    BAR(); LGKM0;                                                                 \
    PRIO1; PMM(0); PRIO0;                                                         \
    BAR();                                                                        \
    /* p2 */                                                                      \
    if (st_) { PSTG_A(u_, (U) + 2); PSTG_B(u_, (U) + 2, 0); PSTG_B(u_, (U) + 2, 1); } \
    BAR(); LGKM0;                                                                 \
    PRIO1; PMM(1); PRIO0;                                                         \
    if (st_) { VMW(6); } else { VMW(0); }                                         \
    BAR();                                                                        \
  }

  // prologue: tiles 0,1 fully staged; drain tile 0 (leave tile 1's 6 in flight)
  PSTG_A(0, 0); PSTG_B(0, 0, 0); PSTG_B(0, 0, 1);
  PSTG_A(1, 1); PSTG_B(1, 1, 0); PSTG_B(1, 1, 1);
  VMW(6);
  BAR();

  for (int j = 0; j < NT / 2; ++j) {
    PHALF(2 * j);
    PHALF(2 * j + 1);
  }
#undef PSTG_A
#undef PSTG_B
#undef PRD_A
#undef PRD_B
#undef PMM
#undef PHALF

  const int er = (lane >> 4) * 4, ec = lane & 15;
  const int r0 = mt * 128 + wm;
  const int c0 = nt * 256 + wn;
  float* C = out + (size_t)z * (2048 * 1024);
  const float* lz = lsum + z * 2048;
#pragma unroll
  for (int mi = 0; mi < 4; ++mi) {
    float inv[4];
#pragma unroll
    for (int r = 0; r < 4; ++r) inv[r] = 1.0f / lz[r0 + mi * 16 + er + r];
#pragma unroll
    for (int ni = 0; ni < 4; ++ni) {
      const int col = c0 + ni * 16 + ec;
#pragma unroll
      for (int r = 0; r < 4; ++r)
        C[(size_t)(r0 + mi * 16 + er + r) * 1024 + col] = acc[mi][ni][r] * inv[r];
    }
  }
}

extern "C" void kernel_launch(void* const* d_in, const int* in_sizes, int n_in,
                              void* d_out, int out_size, void* d_ws, size_t ws_size,
                              hipStream_t stream) {
  const float* x  = (const float*)d_in[0];
  const float* Wq = (const float*)d_in[1];
  const float* bq = (const float*)d_in[2];
  const float* Wk = (const float*)d_in[3];
  const float* bk = (const float*)d_in[4];
  const float* Wv = (const float*)d_in[5];
  const float* bv = (const float*)d_in[6];
  float* out = (float*)d_out;

  char* ws = (char*)d_ws;
  const size_t MB = 1ull << 20;
  u16* Q    = (u16*)(ws + 0 * MB);    // [2][8192][1024] bf16: Q,K contiguous
  u16* Vt   = (u16*)(ws + 48 * MB);   // [4][1024][2048]
  u16* Xb   = (u16*)(ws + 64 * MB);   // [8192][1024]
  u16* Wt   = (u16*)(ws + 80 * MB);   // [3][1024][1024]
  float* bias = (float*)(ws + 86 * MB);  // [3][1024]
  float* lsum = (float*)(ws + 87 * MB);  // [4][2048] softmax denominators
  u16* P    = (u16*)(ws + 88 * MB);   // [4][2048][2048] exp(scores), ends 120MB
  (void)ws_size; (void)in_sizes; (void)n_in; (void)out_size;

  // 1) fused prep: x->bf16, W->Wt, bias gather, lsum zero
  prep<<<11264, 256, 0, stream>>>(x, Wq, Wk, Wv, bq, bk, bv, Xb, Wt, bias, lsum);
  // 2) Q|K projection as one N=2048 GEMM (256 blocks, 4-phase/K-tile)
  qk_proj<<<256, 512, 0, stream>>>(Xb, Wt, Q, bias);
  // 3) Vt projection + P~ = exp(Q K^T) with row sums (384 blocks)
  vt_score<<<384, 512, 0, stream>>>(Xb, Wt, Q, Vt, P, lsum, bias);
  // 4) out = (P~ V) / lsum[row] (256 blocks, 128x256, 2-phase half-iters)
  pv_out<<<256, 512, 0, stream>>>(P, Vt, out, lsum);
}

// Round 5
// 232.696 us; speedup vs baseline: 1.0200x; 1.0200x over previous
//
#include <hip/hip_runtime.h>
#include <hip/hip_bf16.h>
#include <stdint.h>

typedef unsigned short u16;
typedef __attribute__((ext_vector_type(8))) short short8;   // 8 x bf16 (4 VGPRs) MFMA A/B frag
typedef __attribute__((ext_vector_type(4))) float floatx4;  // MFMA C/D frag

#define BATCH 4
#define SEQ   2048
#define DIM   1024

__device__ inline u16 f2bf(float f) {
  union { float f; uint32_t u; } v; v.f = f;
  uint32_t r = v.u + 0x7fffu + ((v.u >> 16) & 1u);  // RNE
  return (u16)(r >> 16);
}

// packed fp32x2 -> bf16x2 (v_cvt_pk_bf16_f32 on gfx950), RNE — bit-identical to f2bf
__device__ inline uint32_t f2bf2(float lo, float hi) {
  __hip_bfloat162 h = __float22bfloat162_rn(float2{lo, hi});
  union { __hip_bfloat162 h; uint32_t u; } v; v.h = h;
  return v.u;
}

// async global->LDS, 16B per lane; LDS dest is wave-uniform base (+lane*16 by HW)
__device__ inline void gload_lds16(const u16* g, u16* l) {
  __builtin_amdgcn_global_load_lds((const __attribute__((address_space(1))) uint32_t*)g,
                                   (__attribute__((address_space(3))) uint32_t*)l,
                                   16, 0, 0);
}

// ---------------- fused prep: x->bf16, W->Wt bf16, bias gather, lsum zero ----------------
// blocks [0,8192): cvt x.  blocks [8192,11264): transpose W (32x32 tile each).
__global__ __launch_bounds__(256) void prep(const float* __restrict__ x,
                                            const float* __restrict__ Wq,
                                            const float* __restrict__ Wk,
                                            const float* __restrict__ Wv,
                                            const float* __restrict__ bq,
                                            const float* __restrict__ bk,
                                            const float* __restrict__ bv,
                                            u16* __restrict__ Xb,
                                            u16* __restrict__ Wt,
                                            float* __restrict__ bias,
                                            float* __restrict__ lsum) {
  __shared__ u16 tile[32][33];
  const int bx = blockIdx.x;
  if (bx < 8192) {
    size_t i = ((size_t)bx * 256 + threadIdx.x) * 4;
    float4 v = *(const float4*)(x + i);
    uint2 o;
    o.x = f2bf2(v.x, v.y);
    o.y = f2bf2(v.z, v.w);
    *(uint2*)(Xb + i) = o;
    if (bx < 8) {  // zero 8192 floats of lsum
      float4 z = {0.f, 0.f, 0.f, 0.f};
      *(float4*)(lsum + (size_t)bx * 1024 + threadIdx.x * 4) = z;
    }
    return;
  }
  const int t = bx - 8192;
  const int tz = t >> 10;            // 0..2  (weight index)
  const int bxx = t & 31;            // 32 col-tiles
  const int byy = (t >> 5) & 31;     // 32 row-tiles
  const float* W = (tz == 0) ? Wq : (tz == 1) ? Wk : Wv;
  u16* o = Wt + (size_t)tz * (1u << 20);
  if (bxx == 0 && byy == 0) {  // pack biases contiguously
    const float* bsrc = (tz == 0) ? bq : (tz == 1) ? bk : bv;
    float4 b4 = *(const float4*)(bsrc + threadIdx.x * 4);
    *(float4*)(bias + tz * 1024 + threadIdx.x * 4) = b4;
  }
  int c0 = bxx * 32, r0 = byy * 32;
  int tx = threadIdx.x & 31, ty = threadIdx.x >> 5;  // ty 0..7
#pragma unroll
  for (int p = 0; p < 4; ++p)
    tile[p * 8 + ty][tx] = f2bf(W[(size_t)(r0 + p * 8 + ty) * DIM + c0 + tx]);
  __syncthreads();
#pragma unroll
  for (int p = 0; p < 4; ++p)
    o[(size_t)(c0 + p * 8 + ty) * DIM + r0 + tx] = tile[tx][p * 8 + ty];
}

// LDS swizzle (both-sides, rule #21): slot s of row r holds source k-chunk s^((r>>1)&3).
// Staging: gload_lds dest stays linear; SOURCE chunk = (lane&3)^((lane>>3)&3) — the XOR key
// (r>>1)&3 is invariant under the +16-row staging stride and all wave row offsets (mult of 8).
// Read: chunk slot = (lane>>4)^((fr>>1)&3), fr=lane&15.  Lanes 0-15 then spread across
// bank-quads 2-way (free, m136) instead of 8-way.  Verified 0 conflicts in rounds 1-4.

// ---------------- fused QKV+Vt projection, TM=128, BK=64 ----------------
// grid (64,8,3).  z in {0,1}: Q/K = Xb x Wt[z] + b, bf16 -> Q (+ 1/32 for z=0).
// z==2: Vt[b][h][s] = (Wv^T x^T + bv), column-demuxed store.
__global__ __launch_bounds__(256, 4)
void qkv_fused(const u16* __restrict__ Xb, const u16* __restrict__ Wt,
               u16* __restrict__ Q, u16* __restrict__ Vt,
               const float* __restrict__ bias) {
  constexpr int K = 1024;
  __shared__ u16 ldsA[128 * 64];   // two slabs of 128x32
  __shared__ u16 ldsB[128 * 64];
  const int lane = threadIdx.x & 63;
  const int wave = threadIdx.x >> 6;
  const int z = blockIdx.z;

  int mt, nt, N;
  const u16 *Ab, *Bb;
  if (z < 2) {             // Q/K projection: A = Xb rows, B = Wt[z] rows
    mt = blockIdx.x; nt = blockIdx.y; N = 1024;
    Ab = Xb + (size_t)mt * 128 * K;
    Bb = Wt + (size_t)z * (1u << 20) + (size_t)nt * 128 * K;
  } else {                 // Vt projection: A = Wv^T rows (h), B = Xb rows (s)
    nt = blockIdx.x; mt = blockIdx.y; N = 8192;
    Ab = Wt + (size_t)2 * (1u << 20) + (size_t)mt * 128 * K;
    Bb = Xb + (size_t)nt * 128 * K;
  }

  const int sr = lane >> 2;
  const int sc = ((lane & 3) ^ ((lane >> 3) & 3)) * 8;   // pre-swizzled source chunk
  const u16* gA0 = Ab + (size_t)(wave * 32 + sr) * K + sc;
  const u16* gB0 = Bb + (size_t)(wave * 32 + sr) * K + sc;
  u16* lA0 = ldsA + wave * 1024;
  u16* lB0 = ldsB + wave * 1024;
  constexpr int SL = 4096;

  const int wm = (wave >> 1) * 64;
  const int wn = (wave & 1) * 64;
  const int fr = lane & 15;
  const int fk = ((lane >> 4) ^ ((fr >> 1) & 3)) * 8;    // swizzled read chunk
  const u16* la = ldsA + (wm + fr) * 32 + fk;
  const u16* lb = ldsB + (wn + fr) * 32 + fk;

  floatx4 acc[4][4] = {};

  for (int kt = 0; kt < K; kt += 64) {
    __syncthreads();
#pragma unroll
    for (int i = 0; i < 2; ++i) {
      gload_lds16(gA0 + kt + (size_t)(16 * i) * K, lA0 + i * 512);
      gload_lds16(gA0 + kt + 32 + (size_t)(16 * i) * K, lA0 + SL + i * 512);
      gload_lds16(gB0 + kt + (size_t)(16 * i) * K, lB0 + i * 512);
      gload_lds16(gB0 + kt + 32 + (size_t)(16 * i) * K, lB0 + SL + i * 512);
    }
    __syncthreads();
#pragma unroll
    for (int ks = 0; ks < 2; ++ks) {
      short8 a[4], b[4];
#pragma unroll
      for (int i = 0; i < 4; ++i) a[i] = *(const short8*)(la + ks * SL + i * 512);
#pragma unroll
      for (int i = 0; i < 4; ++i) b[i] = *(const short8*)(lb + ks * SL + i * 512);
#pragma unroll
      for (int mi = 0; mi < 4; ++mi)
#pragma unroll
        for (int ni = 0; ni < 4; ++ni)
          acc[mi][ni] = __builtin_amdgcn_mfma_f32_16x16x32_bf16(a[mi], b[ni], acc[mi][ni], 0, 0, 0);
    }
  }

  const int er = (lane >> 4) * 4;
  const int ec = lane & 15;
  const int r0 = mt * 128 + wm;
  const int c0 = nt * 128 + wn;

  if (z < 2) {
    u16* C = Q + (size_t)z * (8u << 20);
    const float* bz = bias + z * 1024;
    const float zs = (z == 0) ? 0.03125f : 1.0f;  // fold 1/sqrt(1024) into Q
#pragma unroll
    for (int mi = 0; mi < 4; ++mi)
#pragma unroll
      for (int ni = 0; ni < 4; ++ni) {
        const int col = c0 + ni * 16 + ec;
        const float bb = bz[col];
        const int row = r0 + mi * 16 + er;
        const uint32_t p0 = f2bf2((acc[mi][ni][0] + bb) * zs, (acc[mi][ni][1] + bb) * zs);
        const uint32_t p1 = f2bf2((acc[mi][ni][2] + bb) * zs, (acc[mi][ni][3] + bb) * zs);
        C[(size_t)(row + 0) * N + col] = (u16)p0;
        C[(size_t)(row + 1) * N + col] = (u16)(p0 >> 16);
        C[(size_t)(row + 2) * N + col] = (u16)p1;
        C[(size_t)(row + 3) * N + col] = (u16)(p1 >> 16);
      }
  } else {
    const float* bz = bias + 2 * 1024;  // bv, indexed by row (=h)
#pragma unroll
    for (int mi = 0; mi < 4; ++mi) {
      float bb[4];
#pragma unroll
      for (int r = 0; r < 4; ++r) bb[r] = bz[r0 + mi * 16 + er + r];
#pragma unroll
      for (int ni = 0; ni < 4; ++ni) {
        const int col = c0 + ni * 16 + ec;
        const size_t base = (size_t)(col >> 11) * (1u << 21) + (col & 2047);
        const int row = r0 + mi * 16 + er;
        const uint32_t p0 = f2bf2(acc[mi][ni][0] + bb[0], acc[mi][ni][1] + bb[1]);
        const uint32_t p1 = f2bf2(acc[mi][ni][2] + bb[2], acc[mi][ni][3] + bb[3]);
        Vt[base + (size_t)(row + 0) * 2048] = (u16)p0;
        Vt[base + (size_t)(row + 1) * 2048] = (u16)(p0 >> 16);
        Vt[base + (size_t)(row + 2) * 2048] = (u16)p1;
        Vt[base + (size_t)(row + 3) * 2048] = (u16)(p1 >> 16);
      }
    }
  }
}

// ---------------- bf16 GEMM, BK=64 (two 32-k slabs per barrier pair) ----------------
// C[m][n] = sum_k A[m][k] * Bt[n][k].  Block tile TM x 128.
// EPI 1: exp(acc), bf16 out, atomicAdd per-row sums into lsum.
// EPI 2: acc * (1/lsum[row]), fp32 out.
// SWIZ 2: grid(128,1,z): mt 16, nt 8   (4m x 4n super-tile per XCD, TM=128)
// SWIZ 4: grid(128,1,z): mt 8, nt 16   (TM=256: 4m x 4n per XCD)
template <int EPI, int SWIZ, int TM>
__global__ __launch_bounds__(256, (TM == 256) ? 2 : 4)
void gemm_bt(const u16* __restrict__ A, const u16* __restrict__ Bt,
             void* __restrict__ Cv, float* __restrict__ lsum,
             int M, int N, int K, size_t sA, size_t sB, size_t sC) {
  constexpr int MI = TM / 32;
  constexpr int AS = TM / 64;
  __shared__ u16 ldsA[TM * 64];
  __shared__ u16 ldsB[128 * 64];
  const int lane = threadIdx.x & 63;
  const int wave = threadIdx.x >> 6;

  int mt, nt;
  if (SWIZ == 2) {
    const int lin = blockIdx.x;            // 0..127
    const int c = lin & 7, j = lin >> 3;
    mt = 4 * (c >> 1) + (j & 3);           // 16 m-tiles
    nt = 4 * (c & 1) + (j >> 2);           // 8 n-tiles
  } else {
    const int lin = blockIdx.x;            // 0..127
    const int c = lin & 7, j = lin >> 3;
    mt = 4 * (c & 1) + (j & 3);            // 8 m-tiles
    nt = 4 * (c >> 1) + (j >> 2);          // 16 n-tiles
  }

  const u16* Ab = A + sA * blockIdx.z + (size_t)mt * TM * K;
  const u16* Bb = Bt + sB * blockIdx.z + (size_t)nt * 128 * K;

  const int sr = lane >> 2;
  const int sc = ((lane & 3) ^ ((lane >> 3) & 3)) * 8;   // pre-swizzled source chunk
  const u16* gA0 = Ab + (size_t)(wave * (TM / 4) + sr) * K + sc;
  const u16* gB0 = Bb + (size_t)(wave * 32 + sr) * K + sc;
  u16* lA0 = ldsA + wave * (TM / 4) * 32;
  u16* lB0 = ldsB + wave * 1024;
  constexpr int SLA = TM * 32;
  constexpr int SLB = 4096;

  const int wm = (wave >> 1) * (TM / 2);
  const int wn = (wave & 1) * 64;
  const int fr = lane & 15;
  const int fk = ((lane >> 4) ^ ((fr >> 1) & 3)) * 8;    // swizzled read chunk
  const u16* la = ldsA + (wm + fr) * 32 + fk;
  const u16* lb = ldsB + (wn + fr) * 32 + fk;

  floatx4 acc[MI][4] = {};

  for (int kt = 0; kt < K; kt += 64) {
    __syncthreads();
#pragma unroll
    for (int i = 0; i < AS; ++i) {
      gload_lds16(gA0 + kt + (size_t)(16 * i) * K, lA0 + i * 512);
      gload_lds16(gA0 + kt + 32 + (size_t)(16 * i) * K, lA0 + SLA + i * 512);
    }
#pragma unroll
    for (int i = 0; i < 2; ++i) {
      gload_lds16(gB0 + kt + (size_t)(16 * i) * K, lB0 + i * 512);
      gload_lds16(gB0 + kt + 32 + (size_t)(16 * i) * K, lB0 + SLB + i * 512);
    }
    __syncthreads();
#pragma unroll
    for (int ks = 0; ks < 2; ++ks) {
      short8 a[MI], b[4];
#pragma unroll
      for (int i = 0; i < MI; ++i)
        a[i] = *(const short8*)(la + ks * SLA + i * 512);
#pragma unroll
      for (int i = 0; i < 4; ++i)
        b[i] = *(const short8*)(lb + ks * SLB + i * 512);
#pragma unroll
      for (int mi = 0; mi < MI; ++mi)
#pragma unroll
        for (int ni = 0; ni < 4; ++ni)
          acc[mi][ni] = __builtin_amdgcn_mfma_f32_16x16x32_bf16(a[mi], b[ni], acc[mi][ni], 0, 0, 0);
    }
  }

  const int er = (lane >> 4) * 4;
  const int ec = lane & 15;
  const int r0 = mt * TM + wm;
  const int c0 = nt * 128 + wn;

  if (EPI == 1) {
    // P~ = exp(s) (no max subtraction: |s| bounded, fp32-safe), row sums -> lsum.
    u16* C = (u16*)Cv + sC * blockIdx.z;
    float* lz = lsum + blockIdx.z * 2048;
#pragma unroll
    for (int mi = 0; mi < MI; ++mi) {
      float rs[4] = {0.f, 0.f, 0.f, 0.f};
#pragma unroll
      for (int ni = 0; ni < 4; ++ni) {
        const int col = c0 + ni * 16 + ec;
        const int row = r0 + mi * 16 + er;
        float e[4];
#pragma unroll
        for (int r = 0; r < 4; ++r) {
          e[r] = exp2f(acc[mi][ni][r] * 1.44269504088896340736f);
          rs[r] += e[r];
        }
        const uint32_t p0 = f2bf2(e[0], e[1]);
        const uint32_t p1 = f2bf2(e[2], e[3]);
        C[(size_t)(row + 0) * N + col] = (u16)p0;
        C[(size_t)(row + 1) * N + col] = (u16)(p0 >> 16);
        C[(size_t)(row + 2) * N + col] = (u16)p1;
        C[(size_t)(row + 3) * N + col] = (u16)(p1 >> 16);
      }
#pragma unroll
      for (int o = 1; o < 16; o <<= 1)
#pragma unroll
        for (int r = 0; r < 4; ++r) rs[r] += __shfl_xor(rs[r], o);
      if ((lane & 15) == 0) {
#pragma unroll
        for (int r = 0; r < 4; ++r)
          atomicAdd(&lz[r0 + mi * 16 + er + r], rs[r]);
      }
    }
  } else {
    float* C = (float*)Cv + sC * blockIdx.z;
    const float* lz = lsum + blockIdx.z * 2048;
#pragma unroll
    for (int mi = 0; mi < MI; ++mi) {
      float inv[4];
#pragma unroll
      for (int r = 0; r < 4; ++r) inv[r] = 1.0f / lz[r0 + mi * 16 + er + r];
#pragma unroll
      for (int ni = 0; ni < 4; ++ni) {
        const int col = c0 + ni * 16 + ec;
#pragma unroll
        for (int r = 0; r < 4; ++r) {
          const int row = r0 + mi * 16 + er + r;
          C[(size_t)row * N + col] = acc[mi][ni][r] * inv[r];
        }
      }
    }
  }
}

extern "C" void kernel_launch(void* const* d_in, const int* in_sizes, int n_in,
                              void* d_out, int out_size, void* d_ws, size_t ws_size,
                              hipStream_t stream) {
  const float* x  = (const float*)d_in[0];
  const float* Wq = (const float*)d_in[1];
  const float* bq = (const float*)d_in[2];
  const float* Wk = (const float*)d_in[3];
  const float* bk = (const float*)d_in[4];
  const float* Wv = (const float*)d_in[5];
  const float* bv = (const float*)d_in[6];
  float* out = (float*)d_out;

  char* ws = (char*)d_ws;
  const size_t MB = 1ull << 20;
  u16* Q    = (u16*)(ws + 0 * MB);    // [2][8192][1024] bf16: Q,K contiguous
  u16* Kb   = (u16*)(ws + 16 * MB);
  u16* Vt   = (u16*)(ws + 48 * MB);   // [4][1024][2048]
  u16* Xb   = (u16*)(ws + 64 * MB);   // [8192][1024]
  u16* Wt   = (u16*)(ws + 80 * MB);   // [3][1024][1024]
  float* bias = (float*)(ws + 86 * MB);  // [3][1024]
  float* lsum = (float*)(ws + 87 * MB);  // [4][2048] softmax denominators
  u16* P    = (u16*)(ws + 88 * MB);   // [4][2048][2048] exp(scores), ends 120MB
  (void)Kb; (void)ws_size; (void)in_sizes; (void)n_in; (void)out_size;

  // 1) fused prep: x->bf16, W->Wt, bias gather, lsum zero
  prep<<<11264, 256, 0, stream>>>(x, Wq, Wk, Wv, bq, bk, bv, Xb, Wt, bias, lsum);
  // 2) fused QKV + Vt projection (Q pre-scaled by 1/32), TM=128, swizzled LDS, 4 blk/CU
  qkv_fused<<<dim3(64, 8, 3), 256, 0, stream>>>(Xb, Wt, Q, Vt, bias);
  // 3) P~ = exp(Q K^T), row sums -> lsum.  TM=256 (best end-to-end), swizzled LDS.
  gemm_bt<1, 4, 256><<<dim3(128, 1, 4), 256, 0, stream>>>(
      Q, Kb, P, lsum, 2048, 2048, 1024,
      (size_t)2097152, (size_t)2097152, (size_t)4194304);
  // 4) out = (P~ V) / lsum[row].  TM=128, swizzled LDS, 4 blk/CU.
  gemm_bt<2, 2, 128><<<dim3(128, 1, 4), 256, 0, stream>>>(
      P, Vt, out, lsum, 2048, 1024, 2048,
      (size_t)4194304, (size_t)2097152, (size_t)2097152);
}